// Round 6
// baseline (575.316 us; speedup 1.0000x reference)
//
#include <hip/hip_runtime.h>

#define IN_DIM 256
#define HID 64
#define K_ITERS 10
#define ALPHA 0.1f

constexpr int RPB      = 128;   // rows per bucket (bucket = row >> 7)
constexpr int BCAP     = 4992;  // slots per bucket; counts ~Poisson(4096), cap = +14 sigma
constexpr int OVF_CAP  = 8192;
constexpr int MAXBUCK  = 1024;  // LDS histogram capacity (nbuck = 782 here)
constexpr int BUILD_BLOCKS = 256;

constexpr int MBM = 64;   // MLP: nodes per block (one per lane)
constexpr int MBK = 32;   // MLP: K-tile

// ---------------- W1 transpose: W1[64][256] -> W1T[256][64] ----------------
__global__ __launch_bounds__(256) void w1_transpose(
    const float* __restrict__ W1, float* __restrict__ W1T)
{
  int i = blockIdx.x * 256 + threadIdx.x;   // 16384 total
  int k = i >> 6, h = i & 63;
  W1T[i] = W1[h * IN_DIM + k];
}

// ---------------- MLP v3: Z = relu(x @ W1^T + b1) @ W2^T + b2 ----------------
// wave w owns hid slice [16w,16w+16); lane owns one node. A and B tiles both
// staged in LDS: A reads conflict-free b32, B reads wave-uniform (broadcast).
// Register prefetch of next A+B tiles overlaps HBM latency with compute.
__global__ __launch_bounds__(256) void mlp_v3(
    const float* __restrict__ x, const float* __restrict__ W1T,
    const float* __restrict__ b1, const float* __restrict__ W2,
    const float* __restrict__ b2, float* __restrict__ Z, int n)
{
  __shared__ float As[MBK][MBM + 1];    // [k][node], stride 65 -> conflict-free
  __shared__ float Bs[MBK][HID];        // [k][hid], uniform reads -> broadcast
  __shared__ float part[4][MBM][2];     // per-wave GEMM2 partials

  const int tid  = threadIdx.x;
  const int lane = tid & 63;
  const int w    = __builtin_amdgcn_readfirstlane(tid >> 6);
  const int bm   = blockIdx.x * MBM;

  float acc[16];
  #pragma unroll
  for (int j = 0; j < 16; ++j) acc[j] = 0.f;

  // stage tile 0
  #pragma unroll
  for (int v = 0; v < 2; ++v) {
    int f4 = tid + 256 * v;
    int r = f4 >> 3, q = f4 & 7;          // A: 8 float4 per node row
    int nd = bm + r;
    float4 xv = (nd < n) ? *reinterpret_cast<const float4*>(&x[(size_t)nd * IN_DIM + 4 * q])
                         : make_float4(0.f, 0.f, 0.f, 0.f);
    As[4*q+0][r] = xv.x; As[4*q+1][r] = xv.y; As[4*q+2][r] = xv.z; As[4*q+3][r] = xv.w;
    int kl = f4 >> 4, h4 = f4 & 15;       // B: 16 float4 per k row
    float4 wv = *reinterpret_cast<const float4*>(&W1T[(size_t)kl * HID + 4 * h4]);
    *reinterpret_cast<float4*>(&Bs[kl][4 * h4]) = wv;
  }
  __syncthreads();

  float4 pfA[2], pfB[2];
  const int NT = IN_DIM / MBK;          // 8 tiles
  for (int t = 0; t < NT; ++t) {
    if (t < NT - 1) {                   // issue next-tile loads early
      #pragma unroll
      for (int v = 0; v < 2; ++v) {
        int f4 = tid + 256 * v;
        int r = f4 >> 3, q = f4 & 7;
        int nd = bm + r;
        pfA[v] = (nd < n) ? *reinterpret_cast<const float4*>(
                                &x[(size_t)nd * IN_DIM + (t + 1) * MBK + 4 * q])
                          : make_float4(0.f, 0.f, 0.f, 0.f);
        int kl = f4 >> 4, h4 = f4 & 15;
        pfB[v] = *reinterpret_cast<const float4*>(
                     &W1T[(size_t)((t + 1) * MBK + kl) * HID + 4 * h4]);
      }
    }
    // compute tile t
    #pragma unroll
    for (int k = 0; k < MBK; ++k) {
      float a = As[k][lane];
      const float4* brow = reinterpret_cast<const float4*>(&Bs[k][w * 16]);
      #pragma unroll
      for (int u = 0; u < 4; ++u) {
        float4 bv = brow[u];
        acc[4*u+0] = fmaf(a, bv.x, acc[4*u+0]);
        acc[4*u+1] = fmaf(a, bv.y, acc[4*u+1]);
        acc[4*u+2] = fmaf(a, bv.z, acc[4*u+2]);
        acc[4*u+3] = fmaf(a, bv.w, acc[4*u+3]);
      }
    }
    __syncthreads();
    if (t < NT - 1) {
      #pragma unroll
      for (int v = 0; v < 2; ++v) {
        int f4 = tid + 256 * v;
        int r = f4 >> 3, q = f4 & 7;
        As[4*q+0][r] = pfA[v].x; As[4*q+1][r] = pfA[v].y;
        As[4*q+2][r] = pfA[v].z; As[4*q+3][r] = pfA[v].w;
        int kl = f4 >> 4, h4 = f4 & 15;
        *reinterpret_cast<float4*>(&Bs[kl][4 * h4]) = pfB[v];
      }
      __syncthreads();
    }
  }

  // epilogue: relu(+b1), W2 slice, cross-wave reduce via LDS
  float p0 = 0.f, p1 = 0.f;
  #pragma unroll
  for (int j = 0; j < 16; ++j) {
    float h = acc[j] + b1[w * 16 + j];
    h = fmaxf(h, 0.f);
    p0 = fmaf(h, W2[0 * HID + w * 16 + j], p0);
    p1 = fmaf(h, W2[1 * HID + w * 16 + j], p1);
  }
  part[w][lane][0] = p0;
  part[w][lane][1] = p1;
  __syncthreads();
  if (tid < 2 * MBM) {
    int r = tid >> 1, o = tid & 1;
    float s = part[0][r][o] + part[1][r][o] + part[2][r][o] + part[3][r][o] + b2[o];
    int nd = bm + r;
    if (nd < n) Z[(size_t)nd * 2 + o] = s;
  }
}

// ---------------- Bucket multisplit build ----------------
__global__ __launch_bounds__(512) void bucket_build(
    const int* __restrict__ rows, const int* __restrict__ cols,
    const float* __restrict__ vals, int* __restrict__ gcnt,
    int2* __restrict__ binned, int4* __restrict__ ovf, int* __restrict__ ovfN,
    int e, int nbuck)
{
  __shared__ int h1[MAXBUCK];
  __shared__ int h2[MAXBUCK];
  __shared__ int base[MAXBUCK];
  const int tid = threadIdx.x;
  const int chunk = (e + gridDim.x - 1) / gridDim.x;
  const int beg = blockIdx.x * chunk;
  const int end = min(beg + chunk, e);

  for (int b = tid; b < nbuck; b += 512) { h1[b] = 0; h2[b] = 0; }
  __syncthreads();

  for (int i = beg + tid; i < end; i += 512)
    atomicAdd(&h1[rows[i] >> 7], 1);
  __syncthreads();

  for (int b = tid; b < nbuck; b += 512) {
    int c = h1[b];
    base[b] = c ? atomicAdd(&gcnt[b], c) : 0;
  }
  __syncthreads();

  for (int i = beg + tid; i < end; i += 512) {
    int r = rows[i];
    int b = r >> 7;
    int rank = atomicAdd(&h2[b], 1);
    int pos  = base[b] + rank;
    int rc   = ((r & 127) << 17) | cols[i];
    int vb   = __float_as_int(vals[i]);
    if (pos < BCAP) {
      binned[(size_t)b * BCAP + pos] = make_int2(rc, vb);
    } else {
      int k = atomicAdd(ovfN, 1);
      if (k < OVF_CAP) ovf[k] = make_int4(b, rc, vb, 0);
    }
  }
}

// ---------------- APPNP step: one block per bucket, LDS accumulation ----------------
// int4 reads (2 edges per load) for MLP-level parallelism; 4 accumulator
// replicas (one per 128-thread group) cut same-address atomic serialization.
__global__ __launch_bounds__(512) void bucket_gather(
    const int* __restrict__ gcnt, const int2* __restrict__ binned,
    const float* __restrict__ Z, const float* __restrict__ Hin,
    float* __restrict__ Hout, const int4* __restrict__ ovf,
    const int* __restrict__ ovfN, float cB, int n)
{
  __shared__ float accx[4][RPB];
  __shared__ float accy[4][RPB];
  const int b = blockIdx.x, tid = threadIdx.x;
  reinterpret_cast<float*>(accx)[tid] = 0.f;   // 512 floats each: exact fit
  reinterpret_cast<float*>(accy)[tid] = 0.f;
  __syncthreads();

  float* ax = accx[tid >> 7];
  float* ay = accy[tid >> 7];

  const int cnt = min(gcnt[b], BCAP);
  const int4* bp4 = reinterpret_cast<const int4*>(binned + (size_t)b * BCAP);
  const int npair = cnt >> 1;
  for (int i = tid; i < npair; i += 512) {
    int4 p = bp4[i];
    int colA = p.x & 0x1FFFF, rlA = p.x >> 17;
    int colB = p.z & 0x1FFFF, rlB = p.z >> 17;
    float2 hA = *reinterpret_cast<const float2*>(&Hin[(size_t)colA * 2]);
    float2 hB = *reinterpret_cast<const float2*>(&Hin[(size_t)colB * 2]);
    float vA = __int_as_float(p.y), vB = __int_as_float(p.w);
    atomicAdd(&ax[rlA], vA * hA.x);
    atomicAdd(&ay[rlA], vA * hA.y);
    atomicAdd(&ax[rlB], vB * hB.x);
    atomicAdd(&ay[rlB], vB * hB.y);
  }
  if ((cnt & 1) && tid == 0) {
    int2 p = binned[(size_t)b * BCAP + cnt - 1];
    int col = p.x & 0x1FFFF, rl = p.x >> 17;
    float v = __int_as_float(p.y);
    float2 h = *reinterpret_cast<const float2*>(&Hin[(size_t)col * 2]);
    atomicAdd(&ax[rl], v * h.x);
    atomicAdd(&ay[rl], v * h.y);
  }

  int novf = *ovfN;
  if (novf > 0) {
    novf = min(novf, OVF_CAP);
    for (int j = tid; j < novf; j += 512) {
      int4 o = ovf[j];
      if (o.x == b) {
        int col = o.y & 0x1FFFF, rl = o.y >> 17;
        float v = __int_as_float(o.z);
        float2 h = *reinterpret_cast<const float2*>(&Hin[(size_t)col * 2]);
        atomicAdd(&ax[rl], v * h.x);
        atomicAdd(&ay[rl], v * h.y);
      }
    }
  }
  __syncthreads();

  int r = b * RPB + tid;
  if (tid < RPB && r < n) {
    float sx = accx[0][tid] + accx[1][tid] + accx[2][tid] + accx[3][tid];
    float sy = accy[0][tid] + accy[1][tid] + accy[2][tid] + accy[3][tid];
    float2 z = *reinterpret_cast<const float2*>(&Z[(size_t)r * 2]);
    reinterpret_cast<float2*>(Hout)[r] =
        make_float2(ALPHA * z.x + cB * sx, ALPHA * z.y + cB * sy);
  }
}

extern "C" void kernel_launch(void* const* d_in, const int* in_sizes, int n_in,
                              void* d_out, int out_size, void* d_ws, size_t ws_size,
                              hipStream_t stream) {
  const float* x     = (const float*)d_in[0];
  const float* W1    = (const float*)d_in[1];
  const float* b1    = (const float*)d_in[2];
  const float* W2    = (const float*)d_in[3];
  const float* b2    = (const float*)d_in[4];
  const int*   erows = (const int*)d_in[5];
  const int*   ecols = (const int*)d_in[6];
  const float* evals = (const float*)d_in[7];
  float* out = (float*)d_out;

  const int n = in_sizes[0] / IN_DIM;     // 100000
  const int e = in_sizes[5];              // 3200000
  const int nbuck = (n + RPB - 1) / RPB;  // 782

  // workspace layout (binned first: 16B alignment for int4 reads)
  char* ws = (char*)d_ws;
  int2*  binned = (int2*)ws;   ws += (size_t)nbuck * BCAP * sizeof(int2);
  int4*  ovf    = (int4*)ws;   ws += (size_t)OVF_CAP * sizeof(int4);
  float* Z      = (float*)ws;  ws += (size_t)n * 2 * sizeof(float);
  float* Ha     = (float*)ws;  ws += (size_t)n * 2 * sizeof(float);
  float* Hb     = (float*)ws;  ws += (size_t)n * 2 * sizeof(float);
  float* W1T    = (float*)ws;  ws += (size_t)IN_DIM * HID * sizeof(float);
  int*   gcnt   = (int*)ws;    ws += (size_t)nbuck * sizeof(int);
  int*   ovfN   = (int*)ws;    ws += 4 * sizeof(int);

  hipMemsetAsync(gcnt, 0, (size_t)nbuck * sizeof(int), stream);
  hipMemsetAsync(ovfN, 0, sizeof(int), stream);

  bucket_build<<<BUILD_BLOCKS, 512, 0, stream>>>(erows, ecols, evals, gcnt,
                                                 binned, ovf, ovfN, e, nbuck);

  w1_transpose<<<(IN_DIM * HID) / 256, 256, 0, stream>>>(W1, W1T);
  mlp_v3<<<(n + MBM - 1) / MBM, 256, 0, stream>>>(x, W1T, b1, W2, b2, Z, n);

  const float cB = 1.f - ALPHA;
  const float* hin = Z;
  for (int t = 0; t < K_ITERS; ++t) {
    float* hout = (t == K_ITERS - 1) ? out : ((t & 1) ? Hb : Ha);
    bucket_gather<<<nbuck, 512, 0, stream>>>(gcnt, binned, Z, hin, hout,
                                             ovf, ovfN, cB, n);
    hin = hout;
  }
}

// Round 7
// 524.382 us; speedup vs baseline: 1.0971x; 1.0971x over previous
//
#include <hip/hip_runtime.h>

#define IN_DIM 256
#define HID 64
#define K_ITERS 10
#define ALPHA 0.1f

constexpr int RPB      = 128;   // rows per bucket (bucket = row >> 7)
constexpr int BCAP     = 4992;  // slots per bucket; counts ~Poisson(4096), cap = +14 sigma
constexpr int OVF_CAP  = 8192;
constexpr int MAXBUCK  = 1024;  // LDS histogram capacity (nbuck = 782 here)
constexpr int BUILD_BLOCKS = 256;

constexpr int MBM = 64;   // MLP: nodes per block (one per lane)
constexpr int MBKS = 128; // MLP: staged k half-tile

// ---------------- W1 transpose: W1[64][256] -> W1T[256][64] ----------------
__global__ __launch_bounds__(256) void w1_transpose(
    const float* __restrict__ W1, float* __restrict__ W1T)
{
  int i = blockIdx.x * 256 + threadIdx.x;   // 16384 total
  int k = i >> 6, h = i & 63;
  W1T[i] = W1[h * IN_DIM + k];
}

// ---------------- MLP v4: Z = relu(x @ W1^T + b1) @ W2^T + b2 ----------------
// Lane owns one node; wave w owns hid slice [16w,16w+16). x staged in LDS in
// two 128-k half-tiles (8 float4/thread back-to-back -> deep load pipeline);
// B read wave-uniform from W1T (L1-resident, broadcast). No values held across
// barriers -> no spill.
__global__ __launch_bounds__(256) void mlp_v4(
    const float* __restrict__ x, const float* __restrict__ W1T,
    const float* __restrict__ b1, const float* __restrict__ W2,
    const float* __restrict__ b2, float* __restrict__ Z, int n)
{
  __shared__ float As[MBKS][MBM + 1];   // [k][node], 33.3 KB, read conflict-free
  __shared__ float part[4][MBM][2];

  const int tid  = threadIdx.x;
  const int lane = tid & 63;
  const int w    = tid >> 6;
  const int bm   = blockIdx.x * MBM;

  float acc[16];
  #pragma unroll
  for (int j = 0; j < 16; ++j) acc[j] = 0.f;

  for (int half = 0; half < 2; ++half) {
    const int kbase = half * MBKS;
    // stage: 64 nodes x 128 k = 2048 float4, 8 per thread, all issued up front
    float4 xv[8];
    #pragma unroll
    for (int v = 0; v < 8; ++v) {
      int f4 = tid + 256 * v;
      int r = f4 >> 5, q = f4 & 31;          // 32 float4 per node-row
      int nd = bm + r;
      xv[v] = (nd < n) ? *reinterpret_cast<const float4*>(
                             &x[(size_t)nd * IN_DIM + kbase + 4 * q])
                       : make_float4(0.f, 0.f, 0.f, 0.f);
    }
    #pragma unroll
    for (int v = 0; v < 8; ++v) {
      int f4 = tid + 256 * v;
      int r = f4 >> 5, q = f4 & 31;
      As[4*q+0][r] = xv[v].x; As[4*q+1][r] = xv[v].y;
      As[4*q+2][r] = xv[v].z; As[4*q+3][r] = xv[v].w;
    }
    __syncthreads();

    const float* wt = W1T + (size_t)kbase * HID + w * 16;
    #pragma unroll 4
    for (int k = 0; k < MBKS; ++k) {
      float a = As[k][lane];
      const float4* w4 = reinterpret_cast<const float4*>(wt + (size_t)k * HID);
      #pragma unroll
      for (int u = 0; u < 4; ++u) {
        float4 bv = w4[u];
        acc[4*u+0] = fmaf(a, bv.x, acc[4*u+0]);
        acc[4*u+1] = fmaf(a, bv.y, acc[4*u+1]);
        acc[4*u+2] = fmaf(a, bv.z, acc[4*u+2]);
        acc[4*u+3] = fmaf(a, bv.w, acc[4*u+3]);
      }
    }
    __syncthreads();
  }

  // epilogue: relu(+b1), W2 slice, cross-wave reduce via LDS
  float p0 = 0.f, p1 = 0.f;
  #pragma unroll
  for (int j = 0; j < 16; ++j) {
    float h = acc[j] + b1[w * 16 + j];
    h = fmaxf(h, 0.f);
    p0 = fmaf(h, W2[0 * HID + w * 16 + j], p0);
    p1 = fmaf(h, W2[1 * HID + w * 16 + j], p1);
  }
  part[w][lane][0] = p0;
  part[w][lane][1] = p1;
  __syncthreads();
  if (tid < 2 * MBM) {
    int r = tid >> 1, o = tid & 1;
    float s = part[0][r][o] + part[1][r][o] + part[2][r][o] + part[3][r][o] + b2[o];
    int nd = bm + r;
    if (nd < n) Z[(size_t)nd * 2 + o] = s;
  }
}

// ---------------- Bucket multisplit build (unchanged) ----------------
__global__ __launch_bounds__(512) void bucket_build(
    const int* __restrict__ rows, const int* __restrict__ cols,
    const float* __restrict__ vals, int* __restrict__ gcnt,
    int2* __restrict__ binned, int4* __restrict__ ovf, int* __restrict__ ovfN,
    int e, int nbuck)
{
  __shared__ int h1[MAXBUCK];
  __shared__ int h2[MAXBUCK];
  __shared__ int base[MAXBUCK];
  const int tid = threadIdx.x;
  const int chunk = (e + gridDim.x - 1) / gridDim.x;
  const int beg = blockIdx.x * chunk;
  const int end = min(beg + chunk, e);

  for (int b = tid; b < nbuck; b += 512) { h1[b] = 0; h2[b] = 0; }
  __syncthreads();

  for (int i = beg + tid; i < end; i += 512)
    atomicAdd(&h1[rows[i] >> 7], 1);
  __syncthreads();

  for (int b = tid; b < nbuck; b += 512) {
    int c = h1[b];
    base[b] = c ? atomicAdd(&gcnt[b], c) : 0;
  }
  __syncthreads();

  for (int i = beg + tid; i < end; i += 512) {
    int r = rows[i];
    int b = r >> 7;
    int rank = atomicAdd(&h2[b], 1);
    int pos  = base[b] + rank;
    int rc   = ((r & 127) << 17) | cols[i];
    int vb   = __float_as_int(vals[i]);
    if (pos < BCAP) {
      binned[(size_t)b * BCAP + pos] = make_int2(rc, vb);
    } else {
      int k = atomicAdd(ovfN, 1);
      if (k < OVF_CAP) ovf[k] = make_int4(b, rc, vb, 0);
    }
  }
}

// ---------------- Row-sort each bucket + emit bucket-local CSR offsets ------
// One block per bucket. Edges -> LDS, 128-bin histogram + scan, scatter back
// to the bucket's own global window in row-sorted order (writes stay in a
// 32 KB L2-resident window -> written back once).
__global__ __launch_bounds__(512) void bucket_sort(
    const int* __restrict__ gcnt, int2* __restrict__ binned,
    int* __restrict__ rowoff, int nbuck)
{
  __shared__ int2 buf[BCAP];      // 39.9 KB
  __shared__ int hist[RPB];
  __shared__ int offs[RPB];
  __shared__ int cur[RPB];
  const int b = blockIdx.x, tid = threadIdx.x;
  const int cnt = min(gcnt[b], BCAP);
  int2* gp = binned + (size_t)b * BCAP;

  if (tid < RPB) hist[tid] = 0;
  __syncthreads();
  for (int i = tid; i < cnt; i += 512) {
    int2 e = gp[i];
    buf[i] = e;
    atomicAdd(&hist[e.x >> 17], 1);
  }
  __syncthreads();
  if (tid == 0) {
    int run = 0;
    for (int r = 0; r < RPB; ++r) { offs[r] = run; cur[r] = run; run += hist[r]; }
  }
  __syncthreads();
  if (tid < RPB) rowoff[b * RPB + tid] = offs[tid];
  for (int i = tid; i < cnt; i += 512) {
    int2 e = buf[i];
    int pos = atomicAdd(&cur[e.x >> 17], 1);
    gp[pos] = e;                  // scattered, but within this bucket's window
  }
}

// ---------------- APPNP step: row-segment gather, no atomics ----------------
__global__ __launch_bounds__(256) void sorted_gather(
    const int* __restrict__ rowoff, const int* __restrict__ gcnt,
    const int2* __restrict__ binned, const float* __restrict__ Z,
    const float* __restrict__ Hin, float* __restrict__ Hout,
    const int4* __restrict__ ovf, const int* __restrict__ ovfN,
    float cB, int n)
{
  int g = blockIdx.x * 256 + threadIdx.x;
  int r = g >> 2, l = g & 3;
  if (r >= n) return;
  int b = r >> 7, rl = r & 127;
  int cntraw = gcnt[b];
  int cnt = min(cntraw, BCAP);
  int beg = rowoff[b * RPB + rl];
  int end = (rl == RPB - 1) ? cnt : rowoff[b * RPB + rl + 1];
  const int2* bp = binned + (size_t)b * BCAP;
  float sx = 0.f, sy = 0.f;
  for (int i = beg + l; i < end; i += 4) {
    int2 p = bp[i];
    int col = p.x & 0x1FFFF;
    float v = __int_as_float(p.y);
    float2 h = *reinterpret_cast<const float2*>(&Hin[(size_t)col * 2]);
    sx += v * h.x; sy += v * h.y;
  }
  if (cntraw > BCAP) {            // statistically never taken
    int m = min(*ovfN, OVF_CAP);
    for (int j = l; j < m; j += 4) {
      int4 o = ovf[j];
      if (o.x == b && (o.y >> 17) == rl) {
        int col = o.y & 0x1FFFF;
        float v = __int_as_float(o.z);
        float2 h = *reinterpret_cast<const float2*>(&Hin[(size_t)col * 2]);
        sx += v * h.x; sy += v * h.y;
      }
    }
  }
  sx += __shfl_xor(sx, 1); sy += __shfl_xor(sy, 1);
  sx += __shfl_xor(sx, 2); sy += __shfl_xor(sy, 2);
  if (l == 0) {
    float2 z = *reinterpret_cast<const float2*>(&Z[(size_t)r * 2]);
    reinterpret_cast<float2*>(Hout)[r] =
        make_float2(ALPHA * z.x + cB * sx, ALPHA * z.y + cB * sy);
  }
}

extern "C" void kernel_launch(void* const* d_in, const int* in_sizes, int n_in,
                              void* d_out, int out_size, void* d_ws, size_t ws_size,
                              hipStream_t stream) {
  const float* x     = (const float*)d_in[0];
  const float* W1    = (const float*)d_in[1];
  const float* b1    = (const float*)d_in[2];
  const float* W2    = (const float*)d_in[3];
  const float* b2    = (const float*)d_in[4];
  const int*   erows = (const int*)d_in[5];
  const int*   ecols = (const int*)d_in[6];
  const float* evals = (const float*)d_in[7];
  float* out = (float*)d_out;

  const int n = in_sizes[0] / IN_DIM;     // 100000
  const int e = in_sizes[5];              // 3200000
  const int nbuck = (n + RPB - 1) / RPB;  // 782

  // workspace layout (binned first: 16B alignment)
  char* ws = (char*)d_ws;
  int2*  binned = (int2*)ws;   ws += (size_t)nbuck * BCAP * sizeof(int2);
  int4*  ovf    = (int4*)ws;   ws += (size_t)OVF_CAP * sizeof(int4);
  float* Z      = (float*)ws;  ws += (size_t)n * 2 * sizeof(float);
  float* Ha     = (float*)ws;  ws += (size_t)n * 2 * sizeof(float);
  float* Hb     = (float*)ws;  ws += (size_t)n * 2 * sizeof(float);
  float* W1T    = (float*)ws;  ws += (size_t)IN_DIM * HID * sizeof(float);
  int*   rowoff = (int*)ws;    ws += (size_t)nbuck * RPB * sizeof(int);
  int*   gcnt   = (int*)ws;    ws += (size_t)nbuck * sizeof(int);
  int*   ovfN   = (int*)ws;    ws += 4 * sizeof(int);

  hipMemsetAsync(gcnt, 0, (size_t)nbuck * sizeof(int), stream);
  hipMemsetAsync(ovfN, 0, sizeof(int), stream);

  bucket_build<<<BUILD_BLOCKS, 512, 0, stream>>>(erows, ecols, evals, gcnt,
                                                 binned, ovf, ovfN, e, nbuck);
  bucket_sort<<<nbuck, 512, 0, stream>>>(gcnt, binned, rowoff, nbuck);

  w1_transpose<<<(IN_DIM * HID) / 256, 256, 0, stream>>>(W1, W1T);
  mlp_v4<<<(n + MBM - 1) / MBM, 256, 0, stream>>>(x, W1T, b1, W2, b2, Z, n);

  const float cB = 1.f - ALPHA;
  const int grid_g = (4 * n + 255) / 256;
  const float* hin = Z;
  for (int t = 0; t < K_ITERS; ++t) {
    float* hout = (t == K_ITERS - 1) ? out : ((t & 1) ? Hb : Ha);
    sorted_gather<<<grid_g, 256, 0, stream>>>(rowoff, gcnt, binned, Z, hin, hout,
                                              ovf, ovfN, cB, n);
    hin = hout;
  }
}

// Round 8
// 341.451 us; speedup vs baseline: 1.6849x; 1.5357x over previous
//
#include <hip/hip_runtime.h>

#define IN_DIM 256
#define HID 64
#define K_ITERS 10
#define ALPHA 0.1f

constexpr int RPB      = 128;   // rows per bucket (bucket = row >> 7)
constexpr int BCAP     = 4992;  // slots per bucket; counts ~Poisson(4096)
constexpr int OVF_CAP  = 8192;
constexpr int MAXBUCK  = 1024;
constexpr int BUILD_BLOCKS = 256;

typedef __attribute__((ext_vector_type(8))) short short8v;   // 8 bf16 = 4 VGPR
typedef __attribute__((ext_vector_type(4))) float float4v;   // MFMA acc

__device__ __forceinline__ unsigned short f32_bf16(float f) {
  unsigned u = __float_as_uint(f);
  u += 0x7FFFu + ((u >> 16) & 1u);      // round-to-nearest-even
  return (unsigned short)(u >> 16);
}
__device__ __forceinline__ float bf16_f32(unsigned short h) {
  return __uint_as_float((unsigned)h << 16);
}

// ---------------- W1 -> fragment-ordered bf16 hi/lo planes ----------------
// W1F[plane][ks][ht][lane][i]: element = W1[ht*16+(lane&15)][ks*32+(lane>>4)*8+i]
__global__ __launch_bounds__(256) void w1_frag(
    const float* __restrict__ W1, unsigned short* __restrict__ W1F)
{
  int idx = blockIdx.x * 256 + threadIdx.x;   // 16384
  int i  = idx & 7;
  int ln = (idx >> 3) & 63;
  int ht = (idx >> 9) & 3;
  int ks = idx >> 11;
  int hid = ht * 16 + (ln & 15);
  int k   = ks * 32 + (ln >> 4) * 8 + i;
  float v = W1[hid * IN_DIM + k];
  unsigned short hi = f32_bf16(v);
  unsigned short lo = f32_bf16(v - bf16_f32(hi));
  W1F[idx]         = hi;
  W1F[16384 + idx] = lo;
}

// ---------------- MLP via split-bf16 MFMA ----------------
// Wave w owns nodes [blk*64+16w, +16). No LDS, no barriers. Per K-step:
// A = x rows converted to bf16 hi/lo in-register; B from pre-packed W1F.
// acc += Ahi*Bhi + Alo*Bhi + Ahi*Blo  (lo*lo term ~2^-18, dropped).
__global__ __launch_bounds__(256) void mlp_mfma(
    const float* __restrict__ x, const unsigned short* __restrict__ W1F,
    const float* __restrict__ b1, const float* __restrict__ W2,
    const float* __restrict__ b2, float* __restrict__ Z, int n)
{
  const int tid  = threadIdx.x;
  const int w    = tid >> 6;
  const int lane = tid & 63;
  const int m    = lane & 15;        // C col / A row
  const int kg   = lane >> 4;        // k-group, C row block
  const int node = blockIdx.x * 64 + w * 16 + m;
  const bool valid = node < n;
  const float* xrow = x + (size_t)(valid ? node : 0) * IN_DIM;

  const short8v* Bhi = reinterpret_cast<const short8v*>(W1F);
  const short8v* Blo = Bhi + 2048;   // 16384 ushort = 2048 short8

  float4v acc[4];
  #pragma unroll
  for (int ht = 0; ht < 4; ++ht) acc[ht] = (float4v){0.f, 0.f, 0.f, 0.f};

  #pragma unroll
  for (int ks = 0; ks < 8; ++ks) {
    const int kb = ks * 32 + kg * 8;
    float4 a0 = *reinterpret_cast<const float4*>(xrow + kb);
    float4 a1 = *reinterpret_cast<const float4*>(xrow + kb + 4);
    float xv[8] = {a0.x, a0.y, a0.z, a0.w, a1.x, a1.y, a1.z, a1.w};
    short8v ahi, alo;
    #pragma unroll
    for (int i = 0; i < 8; ++i) {
      unsigned short h = f32_bf16(xv[i]);
      ahi[i] = (short)h;
      alo[i] = (short)f32_bf16(xv[i] - bf16_f32(h));
    }
    #pragma unroll
    for (int ht = 0; ht < 4; ++ht) {
      int bidx = (ks * 4 + ht) * 64 + lane;
      short8v bh = Bhi[bidx];
      short8v bl = Blo[bidx];
      acc[ht] = __builtin_amdgcn_mfma_f32_16x16x32_bf16(ahi, bh, acc[ht], 0, 0, 0);
      acc[ht] = __builtin_amdgcn_mfma_f32_16x16x32_bf16(alo, bh, acc[ht], 0, 0, 0);
      acc[ht] = __builtin_amdgcn_mfma_f32_16x16x32_bf16(ahi, bl, acc[ht], 0, 0, 0);
    }
  }

  // GEMM2 fused: h[node][hid] -> Z[node][2]. Lane holds hid=ht*16+m for 4 nodes
  // (rows kg*4+j). Partial over its 4 hids, then reduce across the 16 m-lanes.
  float p0[4] = {0.f, 0.f, 0.f, 0.f}, p1[4] = {0.f, 0.f, 0.f, 0.f};
  #pragma unroll
  for (int ht = 0; ht < 4; ++ht) {
    int hid = ht * 16 + m;
    float w0 = W2[hid], w1v = W2[HID + hid], bb = b1[hid];
    #pragma unroll
    for (int j = 0; j < 4; ++j) {
      float h = fmaxf(acc[ht][j] + bb, 0.f);
      p0[j] = fmaf(h, w0, p0[j]);
      p1[j] = fmaf(h, w1v, p1[j]);
    }
  }
  #pragma unroll
  for (int j = 0; j < 4; ++j) {
    #pragma unroll
    for (int s = 1; s < 16; s <<= 1) {
      p0[j] += __shfl_xor(p0[j], s);
      p1[j] += __shfl_xor(p1[j], s);
    }
  }
  if (m == 0) {
    #pragma unroll
    for (int j = 0; j < 4; ++j) {
      int nd = blockIdx.x * 64 + w * 16 + kg * 4 + j;
      if (nd < n) {
        Z[(size_t)nd * 2 + 0] = p0[j] + b2[0];
        Z[(size_t)nd * 2 + 1] = p1[j] + b2[1];
      }
    }
  }
}

// ---------------- Bucket multisplit build (unchanged) ----------------
__global__ __launch_bounds__(512) void bucket_build(
    const int* __restrict__ rows, const int* __restrict__ cols,
    const float* __restrict__ vals, int* __restrict__ gcnt,
    int2* __restrict__ binned, int4* __restrict__ ovf, int* __restrict__ ovfN,
    int e, int nbuck)
{
  __shared__ int h1[MAXBUCK];
  __shared__ int h2[MAXBUCK];
  __shared__ int base[MAXBUCK];
  const int tid = threadIdx.x;
  const int chunk = (e + gridDim.x - 1) / gridDim.x;
  const int beg = blockIdx.x * chunk;
  const int end = min(beg + chunk, e);

  for (int b = tid; b < nbuck; b += 512) { h1[b] = 0; h2[b] = 0; }
  __syncthreads();

  for (int i = beg + tid; i < end; i += 512)
    atomicAdd(&h1[rows[i] >> 7], 1);
  __syncthreads();

  for (int b = tid; b < nbuck; b += 512) {
    int c = h1[b];
    base[b] = c ? atomicAdd(&gcnt[b], c) : 0;
  }
  __syncthreads();

  for (int i = beg + tid; i < end; i += 512) {
    int r = rows[i];
    int b = r >> 7;
    int rank = atomicAdd(&h2[b], 1);
    int pos  = base[b] + rank;
    int rc   = ((r & 127) << 17) | cols[i];
    int vb   = __float_as_int(vals[i]);
    if (pos < BCAP) {
      binned[(size_t)b * BCAP + pos] = make_int2(rc, vb);
    } else {
      int k = atomicAdd(ovfN, 1);
      if (k < OVF_CAP) ovf[k] = make_int4(b, rc, vb, 0);
    }
  }
}

// ---------------- Row-sort each bucket + bucket-local CSR offsets ----------
__global__ __launch_bounds__(512) void bucket_sort(
    const int* __restrict__ gcnt, int2* __restrict__ binned,
    int* __restrict__ rowoff, int nbuck)
{
  __shared__ int2 buf[BCAP];
  __shared__ int hist[RPB];
  __shared__ int offs[RPB];
  __shared__ int cur[RPB];
  const int b = blockIdx.x, tid = threadIdx.x;
  const int cnt = min(gcnt[b], BCAP);
  int2* gp = binned + (size_t)b * BCAP;

  if (tid < RPB) hist[tid] = 0;
  __syncthreads();
  for (int i = tid; i < cnt; i += 512) {
    int2 e = gp[i];
    buf[i] = e;
    atomicAdd(&hist[e.x >> 17], 1);
  }
  __syncthreads();
  if (tid == 0) {
    int run = 0;
    for (int r = 0; r < RPB; ++r) { offs[r] = run; cur[r] = run; run += hist[r]; }
  }
  __syncthreads();
  if (tid < RPB) rowoff[b * RPB + tid] = offs[tid];
  for (int i = tid; i < cnt; i += 512) {
    int2 e = buf[i];
    int pos = atomicAdd(&cur[e.x >> 17], 1);
    gp[pos] = e;
  }
}

// ---------------- APPNP step: row-segment gather, no atomics ----------------
__global__ __launch_bounds__(256) void sorted_gather(
    const int* __restrict__ rowoff, const int* __restrict__ gcnt,
    const int2* __restrict__ binned, const float* __restrict__ Z,
    const float* __restrict__ Hin, float* __restrict__ Hout,
    const int4* __restrict__ ovf, const int* __restrict__ ovfN,
    float cB, int n)
{
  int g = blockIdx.x * 256 + threadIdx.x;
  int r = g >> 2, l = g & 3;
  if (r >= n) return;
  int b = r >> 7, rl = r & 127;
  int cntraw = gcnt[b];
  int cnt = min(cntraw, BCAP);
  int beg = rowoff[b * RPB + rl];
  int end = (rl == RPB - 1) ? cnt : rowoff[b * RPB + rl + 1];
  const int2* bp = binned + (size_t)b * BCAP;
  float sx = 0.f, sy = 0.f;
  for (int i = beg + l; i < end; i += 4) {
    int2 p = bp[i];
    int col = p.x & 0x1FFFF;
    float v = __int_as_float(p.y);
    float2 h = *reinterpret_cast<const float2*>(&Hin[(size_t)col * 2]);
    sx += v * h.x; sy += v * h.y;
  }
  if (cntraw > BCAP) {
    int mo = min(*ovfN, OVF_CAP);
    for (int j = l; j < mo; j += 4) {
      int4 o = ovf[j];
      if (o.x == b && (o.y >> 17) == rl) {
        int col = o.y & 0x1FFFF;
        float v = __int_as_float(o.z);
        float2 h = *reinterpret_cast<const float2*>(&Hin[(size_t)col * 2]);
        sx += v * h.x; sy += v * h.y;
      }
    }
  }
  sx += __shfl_xor(sx, 1); sy += __shfl_xor(sy, 1);
  sx += __shfl_xor(sx, 2); sy += __shfl_xor(sy, 2);
  if (l == 0) {
    float2 z = *reinterpret_cast<const float2*>(&Z[(size_t)r * 2]);
    reinterpret_cast<float2*>(Hout)[r] =
        make_float2(ALPHA * z.x + cB * sx, ALPHA * z.y + cB * sy);
  }
}

extern "C" void kernel_launch(void* const* d_in, const int* in_sizes, int n_in,
                              void* d_out, int out_size, void* d_ws, size_t ws_size,
                              hipStream_t stream) {
  const float* x     = (const float*)d_in[0];
  const float* W1    = (const float*)d_in[1];
  const float* b1    = (const float*)d_in[2];
  const float* W2    = (const float*)d_in[3];
  const float* b2    = (const float*)d_in[4];
  const int*   erows = (const int*)d_in[5];
  const int*   ecols = (const int*)d_in[6];
  const float* evals = (const float*)d_in[7];
  float* out = (float*)d_out;

  const int n = in_sizes[0] / IN_DIM;     // 100000
  const int e = in_sizes[5];              // 3200000
  const int nbuck = (n + RPB - 1) / RPB;  // 782

  // workspace layout (16B-aligned blocks in declaration order)
  char* ws = (char*)d_ws;
  int2*  binned = (int2*)ws;            ws += (size_t)nbuck * BCAP * sizeof(int2);
  int4*  ovf    = (int4*)ws;            ws += (size_t)OVF_CAP * sizeof(int4);
  float* Z      = (float*)ws;           ws += (size_t)n * 2 * sizeof(float);
  float* Ha     = (float*)ws;           ws += (size_t)n * 2 * sizeof(float);
  float* Hb     = (float*)ws;           ws += (size_t)n * 2 * sizeof(float);
  unsigned short* W1F = (unsigned short*)ws;  ws += 2 * 16384 * sizeof(unsigned short);
  int*   rowoff = (int*)ws;             ws += (size_t)nbuck * RPB * sizeof(int);
  int*   gcnt   = (int*)ws;             ws += (size_t)nbuck * sizeof(int);
  int*   ovfN   = (int*)ws;             ws += 4 * sizeof(int);

  hipMemsetAsync(gcnt, 0, (size_t)nbuck * sizeof(int), stream);
  hipMemsetAsync(ovfN, 0, sizeof(int), stream);

  bucket_build<<<BUILD_BLOCKS, 512, 0, stream>>>(erows, ecols, evals, gcnt,
                                                 binned, ovf, ovfN, e, nbuck);
  bucket_sort<<<nbuck, 512, 0, stream>>>(gcnt, binned, rowoff, nbuck);

  w1_frag<<<64, 256, 0, stream>>>(W1, W1F);
  mlp_mfma<<<(n + 63) / 64, 256, 0, stream>>>(x, W1F, b1, W2, b2, Z, n);

  const float cB = 1.f - ALPHA;
  const int grid_g = (4 * n + 255) / 256;
  const float* hin = Z;
  for (int t = 0; t < K_ITERS; ++t) {
    float* hout = (t == K_ITERS - 1) ? out : ((t & 1) ? Hb : Ha);
    sorted_gather<<<grid_g, 256, 0, stream>>>(rowoff, gcnt, binned, Z, hin, hout,
                                              ovf, ovfN, cB, n);
    hin = hout;
  }
}